// Round 6
// baseline (977.384 us; speedup 1.0000x reference)
//
#include <hip/hip_runtime.h>
#include <hip/hip_bf16.h>

#define N_NODES 10000
#define N_EDGES 160000
#define HID 300
#define HIDP 304   // padded hidden dim (Part A buffers)
#define NPARTB (N_EDGES - N_NODES)   // 150000 independent rows
#define RB 48      // rows per GCN block (3 M-tiles)
#define KS 328     // H-plane k-stride in shorts

typedef __attribute__((ext_vector_type(8))) short short8;
typedef __attribute__((ext_vector_type(4))) float f32x4;

#define MFMA_B16(a, b, c) __builtin_amdgcn_mfma_f32_16x16x32_bf16(a, b, c, 0, 0, 0)

__device__ __forceinline__ void split1(float x, short& hi, short& lo) {
    unsigned u = __float_as_uint(x);
    unsigned h = (u + 0x7fffu + ((u >> 16) & 1u)) >> 16;
    float hf = __uint_as_float(h << 16);
    float d = x - hf;
    unsigned v = __float_as_uint(d);
    unsigned l = (v + 0x7fffu + ((v >> 16) & 1u)) >> 16;
    hi = (short)h;
    lo = (short)l;
}

// ---------------------------------------------------------------------------
// prep kernels
// ---------------------------------------------------------------------------

__global__ void k_count(const int* __restrict__ col, int* __restrict__ cnt) {
    int e = blockIdx.x * 256 + threadIdx.x;
    if (e < N_EDGES) atomicAdd(&cnt[col[e]], 1);
}

__global__ void k_scan(const int* __restrict__ cnt, int* __restrict__ col_start,
                       int* __restrict__ cursor, float* __restrict__ dinv,
                       float* __restrict__ selfnorm) {
    __shared__ int wsum[4];
    int t = threadIdx.x;
    int lane = t & 63, w = t >> 6;
    int carry = 0;
    for (int base = 0; base < N_NODES; base += 256) {
        int i = base + t;
        int v = (i < N_NODES) ? cnt[i] : 0;
        int s = v;
#pragma unroll
        for (int d = 1; d < 64; d <<= 1) {
            int n = __shfl_up(s, d, 64);
            if (lane >= d) s += n;
        }
        if (lane == 63) wsum[w] = s;
        __syncthreads();
        int woff = 0;
#pragma unroll
        for (int k = 0; k < 4; ++k)
            if (k < w) woff += wsum[k];
        int total = wsum[0] + wsum[1] + wsum[2] + wsum[3];
        if (i < N_NODES) {
            int excl = carry + woff + s - v;
            col_start[i] = excl;
            cursor[i] = excl;
            float dd = (float)v + 1.0f;
            dinv[i] = rsqrtf(dd);
            selfnorm[i] = 1.0f / dd;
        }
        carry += total;
        __syncthreads();
    }
    if (t == 0) col_start[N_NODES] = carry;
}

// CSR holds packed (row, norm)
__global__ void k_fill(const int* __restrict__ row, const int* __restrict__ col,
                       int* __restrict__ cursor, const float* __restrict__ dinv,
                       int2* __restrict__ edge_pack) {
    int e = blockIdx.x * 256 + threadIdx.x;
    if (e < N_EDGES) {
        int c = col[e], r = row[e];
        int p = atomicAdd(&cursor[c], 1);
        edge_pack[p] = make_int2(r, __float_as_int(dinv[r] * dinv[c]));
    }
}

// ---------------------------------------------------------------------------
// Weight pre-split (layout verified R2-R5):
// wt0 [nt:19][h:2][q:4][n16:16][j:8] shorts; wtl [l:4][chunk:10][nt:19][...]
// ---------------------------------------------------------------------------
__global__ void k_wt(const float* __restrict__ g0w, const float* __restrict__ gw,
                     short* __restrict__ wt0, short* __restrict__ wtl) {
    int idx = blockIdx.x * 256 + threadIdx.x;
    if (idx < 1216) {
        int n16 = idx & 15, q = (idx >> 4) & 3, nt = idx >> 6;
        int n = nt * 16 + n16;
        short* hd = wt0 + (size_t)(nt * 8 + q) * 128 + n16 * 8;
        short* ld = wt0 + (size_t)(nt * 8 + 4 + q) * 128 + n16 * 8;
#pragma unroll
        for (int j = 0; j < 8; ++j) {
            int k = q * 8 + j;
            float f = (n < HID) ? g0w[k * HID + n] : 0.0f;
            short hi, lo;
            split1(f, hi, lo);
            hd[j] = hi;
            ld[j] = lo;
        }
    } else if (idx < 1216 + 48640) {
        int i = idx - 1216;
        int n16 = i & 15; i >>= 4;
        int q = i & 3; i >>= 2;
        int nt = i % 19; i /= 19;
        int chunk = i % 10;
        int l = i / 10;
        int n = nt * 16 + n16;
        int cnt_idx = chunk * 19 + nt;
        short* base = wtl + (size_t)l * 194560;
        short* hd = base + (size_t)(cnt_idx * 8 + q) * 128 + n16 * 8;
        short* ld = base + (size_t)(cnt_idx * 8 + 4 + q) * 128 + n16 * 8;
#pragma unroll
        for (int j = 0; j < 8; ++j) {
            int k = chunk * 32 + q * 8 + j;
            float f = (k < HID && n < HID) ? gw[((size_t)l * HID + k) * HID + n] : 0.0f;
            short hi, lo;
            split1(f, hi, lo);
            hd[j] = hi;
            ld[j] = lo;
        }
    }
}

// ---------------------------------------------------------------------------
// GCN building blocks. 8 waves / 48 rows / H pre-split hi-lo planes in LDS.
// k-loop: runtime loop (#pragma unroll 1 — bounds scheduler hoisting, the
// R5 spill lesson) with explicit B double-buffer rotation (B = long-latency
// L2 load; issued one 27-MFMA burst ahead). A ds_reads issued just before
// use — fine-grained lgkmcnt + 4 waves/SIMD cover their latency.
// Regs: B 48 + A 24 + acc 36(AGPR) ~= 110 < 128 cap (launch_bounds 512,4).
// ---------------------------------------------------------------------------

__device__ __forceinline__ void loadA(const short* Hh, const short* Hl, int l16, int kb,
                                      short8 (&ah)[3], short8 (&al)[3]) {
#pragma unroll
    for (int mt = 0; mt < 3; ++mt) {
        int off = (mt * 16 + l16) * KS + kb;
        ah[mt] = *(const short8*)&Hh[off];
        al[mt] = *(const short8*)&Hl[off];
    }
}

template <int NTC>
__device__ __forceinline__ void loadB(const short* __restrict__ wp, int chunk,
                                      int nt0, int quad, int l16,
                                      short8 (&bh)[NTC], short8 (&bl)[NTC]) {
    const short* cb = wp + (size_t)(chunk * 19 + nt0) * 1024 + quad * 128 + l16 * 8;
#pragma unroll
    for (int i = 0; i < NTC; ++i) {
        bh[i] = *(const short8*)(cb + (size_t)i * 1024);
        bl[i] = *(const short8*)(cb + (size_t)i * 1024 + 512);
    }
}

template <int NTC>
__device__ __forceinline__ void domfma(const short8 (&ah)[3], const short8 (&al)[3],
                                       const short8 (&bh)[NTC], const short8 (&bl)[NTC],
                                       f32x4 (&acc)[3][3]) {
#pragma unroll
    for (int mt = 0; mt < 3; ++mt)
#pragma unroll
        for (int i = 0; i < NTC; ++i) {
            acc[mt][i] = MFMA_B16(ah[mt], bh[i], acc[mt][i]);
            acc[mt][i] = MFMA_B16(ah[mt], bl[i], acc[mt][i]);
            acc[mt][i] = MFMA_B16(al[mt], bh[i], acc[mt][i]);
        }
}

template <int NTC>
__device__ __forceinline__ void zacc(f32x4 (&acc)[3][3]) {
#pragma unroll
    for (int mt = 0; mt < 3; ++mt)
#pragma unroll
        for (int i = 0; i < NTC; ++i)
#pragma unroll
            for (int r = 0; r < 4; ++r) acc[mt][i][r] = 0.0f;
}

template <int NTC>
__device__ __forceinline__ void gcn_kloop1(const short* __restrict__ wp,
                                           const short* Hh, const short* Hl,
                                           int nt0, int quad, int l16,
                                           f32x4 (&acc)[3][3]) {
    zacc<NTC>(acc);
    short8 bh[NTC], bl[NTC], ah[3], al[3];
    loadB<NTC>(wp, 0, nt0, quad, l16, bh, bl);
    loadA(Hh, Hl, l16, quad * 8, ah, al);
    domfma<NTC>(ah, al, bh, bl, acc);
}

template <int NTC>
__device__ __forceinline__ void gcn_kloop10(const short* __restrict__ wp,
                                            const short* Hh, const short* Hl,
                                            int nt0, int quad, int l16,
                                            f32x4 (&acc)[3][3]) {
    zacc<NTC>(acc);
    short8 b0h[NTC], b0l[NTC], b1h[NTC], b1l[NTC], ah[3], al[3];
    loadB<NTC>(wp, 0, nt0, quad, l16, b0h, b0l);
#pragma unroll 1
    for (int c = 0; c < 10; c += 2) {
        loadA(Hh, Hl, l16, c * 32 + quad * 8, ah, al);
        loadB<NTC>(wp, c + 1, nt0, quad, l16, b1h, b1l);   // prefetch (hidden under burst)
        domfma<NTC>(ah, al, b0h, b0l, acc);
        loadA(Hh, Hl, l16, (c + 1) * 32 + quad * 8, ah, al);
        if (c + 2 < 10) loadB<NTC>(wp, c + 2, nt0, quad, l16, b0h, b0l);
        domfma<NTC>(ah, al, b1h, b1l, acc);
    }
}

template <int NTC>
__device__ __forceinline__ void gcn_epilogue(const float* __restrict__ bias,
                                             int nt0, int quad, int l16,
                                             f32x4 (&acc)[3][3],
                                             short* Hh, short* Hl) {
#pragma unroll
    for (int i = 0; i < NTC; ++i) {
        int c = (nt0 + i) * 16 + l16;
        float b = (c < HID) ? bias[c] : 0.0f;
#pragma unroll
        for (int mt = 0; mt < 3; ++mt)
#pragma unroll
            for (int r = 0; r < 4; ++r) {
                float v = fmaxf(acc[mt][i][r] + b, 0.0f);
                short hi, lo;
                split1(v, hi, lo);
                int off = (mt * 16 + quad * 4 + r) * KS + c;
                Hh[off] = hi;
                Hl[off] = lo;
            }
    }
}

template <int NTC>
__device__ __forceinline__ void gcn_final(const float* __restrict__ bias,
                                          int nt0, int quad, int l16, int slot,
                                          f32x4 (&acc)[3][3],
                                          float* __restrict__ g_part) {
#pragma unroll
    for (int i = 0; i < NTC; ++i) {
        int c = (nt0 + i) * 16 + l16;
        float b = (c < HID) ? bias[c] : 0.0f;
        float s = 0.0f;
#pragma unroll
        for (int mt = 0; mt < 3; ++mt)
#pragma unroll
            for (int r = 0; r < 4; ++r) s += fmaxf(acc[mt][i][r] + b, 0.0f);
        s += __shfl_xor(s, 16, 64);
        s += __shfl_xor(s, 32, 64);
        if (quad == 0 && c < HID)
            atomicAdd(&g_part[slot * HIDP + c], s);
    }
}

// ---------------------------------------------------------------------------
// Part B: fused 5-layer; edge-embedding computed inline.
// ---------------------------------------------------------------------------
__global__ __launch_bounds__(512, 4) void k_partB_mfma(
    const float* __restrict__ edge_attr,
    const float* __restrict__ edge_w,
    const float* __restrict__ edge_b,
    const short* __restrict__ wt0,
    const short* __restrict__ wtl,
    const float* __restrict__ b0,
    const float* __restrict__ gb,
    float* __restrict__ g_part) {
    __shared__ short Hh[RB * KS];
    __shared__ short Hl[RB * KS];
    int t = threadIdx.x;
    int lane = t & 63, w = t >> 6;
    int l16 = lane & 15, quad = lane >> 4;
    int base = N_NODES + blockIdx.x * RB;
    int nt0 = (w < 3) ? w * 3 : 9 + (w - 3) * 2;

    if (t < 384) {
        int r = t >> 3, c4 = (t & 7) * 4;
        const float* ar = edge_attr + (size_t)(base + r) * 3;
        float a0 = ar[0], a1 = ar[1], a2 = ar[2];
#pragma unroll
        for (int j = 0; j < 4; ++j) {
            int cc = c4 + j;
            float v = edge_b[cc];
            v = fmaf(a0, edge_w[cc], v);
            v = fmaf(a1, edge_w[32 + cc], v);
            v = fmaf(a2, edge_w[64 + cc], v);
            short hi, lo;
            split1(v, hi, lo);
            Hh[r * KS + cc] = hi;
            Hl[r * KS + cc] = lo;
        }
    }
    for (int i = t; i < RB * 24; i += 512) {
        int r = i / 24, k = 304 + i % 24;
        Hh[r * KS + k] = 0;
        Hl[r * KS + k] = 0;
    }
    __syncthreads();

    f32x4 acc[3][3];
    if (w < 3) gcn_kloop1<3>(wt0, Hh, Hl, nt0, quad, l16, acc);
    else       gcn_kloop1<2>(wt0, Hh, Hl, nt0, quad, l16, acc);
    __syncthreads();
    if (w < 3) gcn_epilogue<3>(b0, nt0, quad, l16, acc, Hh, Hl);
    else       gcn_epilogue<2>(b0, nt0, quad, l16, acc, Hh, Hl);
    __syncthreads();

    for (int l = 0; l < 4; ++l) {
        const short* wp = wtl + (size_t)l * 194560;
        const float* bias = gb + l * HID;
        if (w < 3) gcn_kloop10<3>(wp, Hh, Hl, nt0, quad, l16, acc);
        else       gcn_kloop10<2>(wp, Hh, Hl, nt0, quad, l16, acc);
        __syncthreads();
        if (l < 3) {
            if (w < 3) gcn_epilogue<3>(bias, nt0, quad, l16, acc, Hh, Hl);
            else       gcn_epilogue<2>(bias, nt0, quad, l16, acc, Hh, Hl);
            __syncthreads();
        } else {
            int slot = (blockIdx.x + w) & 63;
            if (w < 3) gcn_final<3>(bias, nt0, quad, l16, slot, acc, g_part);
            else       gcn_final<2>(bias, nt0, quad, l16, slot, acc, g_part);
        }
    }
}

// ---------------------------------------------------------------------------
// Part A GEMM
// ---------------------------------------------------------------------------
template <int NTC>
__device__ __forceinline__ void gemm_out(int base, int nt0, int quad, int l16,
                                         f32x4 (&acc)[3][3], float* __restrict__ HW) {
#pragma unroll
    for (int i = 0; i < NTC; ++i) {
        int c = (nt0 + i) * 16 + l16;
#pragma unroll
        for (int mt = 0; mt < 3; ++mt)
#pragma unroll
            for (int r = 0; r < 4; ++r) {
                int gm = base + mt * 16 + quad * 4 + r;
                if (gm < N_NODES) HW[(size_t)gm * HIDP + c] = acc[mt][i][r];
            }
    }
}

template <bool L0>
__global__ __launch_bounds__(512, 4) void k_gemmA(
    const float* __restrict__ A,
    const float* __restrict__ edge_attr,
    const float* __restrict__ edge_w,
    const float* __restrict__ edge_b,
    const short* __restrict__ wt,
    float* __restrict__ HW) {
    __shared__ short Hh[RB * KS];
    __shared__ short Hl[RB * KS];
    int t = threadIdx.x;
    int lane = t & 63, w = t >> 6;
    int l16 = lane & 15, quad = lane >> 4;
    int base = blockIdx.x * RB;
    int nt0 = (w < 3) ? w * 3 : 9 + (w - 3) * 2;

    if (L0) {
        if (t < 384) {
            int r = t >> 3, c4 = (t & 7) * 4;
            int gr = base + r;
            float a0 = 0.f, a1 = 0.f, a2 = 0.f;
            if (gr < N_NODES) {
                const float* ar = edge_attr + (size_t)gr * 3;
                a0 = ar[0]; a1 = ar[1]; a2 = ar[2];
            }
#pragma unroll
            for (int j = 0; j < 4; ++j) {
                int cc = c4 + j;
                float v = 0.0f;
                if (gr < N_NODES) {
                    v = edge_b[cc];
                    v = fmaf(a0, edge_w[cc], v);
                    v = fmaf(a1, edge_w[32 + cc], v);
                    v = fmaf(a2, edge_w[64 + cc], v);
                }
                short hi, lo;
                split1(v, hi, lo);
                Hh[r * KS + cc] = hi;
                Hl[r * KS + cc] = lo;
            }
        }
    } else {
        const int nc4 = HIDP / 4;  // 76
        for (int idx = t; idx < RB * nc4; idx += 512) {
            int r = idx / nc4, c4 = (idx % nc4) * 4;
            int gr = base + r;
            float a4[4] = {0.0f, 0.0f, 0.0f, 0.0f};
            if (gr < N_NODES) {
                float4 v = *(const float4*)(A + (size_t)gr * HIDP + c4);
                a4[0] = v.x; a4[1] = v.y; a4[2] = v.z; a4[3] = v.w;
            }
#pragma unroll
            for (int j = 0; j < 4; ++j) {
                short hi, lo;
                split1(a4[j], hi, lo);
                Hh[r * KS + c4 + j] = hi;
                Hl[r * KS + c4 + j] = lo;
            }
        }
    }
    for (int i = t; i < RB * 24; i += 512) {
        int r = i / 24, k = 304 + i % 24;
        Hh[r * KS + k] = 0;
        Hl[r * KS + k] = 0;
    }
    __syncthreads();

    f32x4 acc[3][3];
    if (L0) {
        if (w < 3) gcn_kloop1<3>(wt, Hh, Hl, nt0, quad, l16, acc);
        else       gcn_kloop1<2>(wt, Hh, Hl, nt0, quad, l16, acc);
    } else {
        if (w < 3) gcn_kloop10<3>(wt, Hh, Hl, nt0, quad, l16, acc);
        else       gcn_kloop10<2>(wt, Hh, Hl, nt0, quad, l16, acc);
    }
    if (w < 3) gemm_out<3>(base, nt0, quad, l16, acc, HW);
    else       gemm_out<2>(base, nt0, quad, l16, acc, HW);
}

// ---------------------------------------------------------------------------
// Part A aggregation: wave per node, packed (row,norm) records, 4-edge batches.
// ---------------------------------------------------------------------------
__global__ __launch_bounds__(256) void k_aggA(
    const float* __restrict__ hw, const int* __restrict__ col_start,
    const int2* __restrict__ edge_pack, const float* __restrict__ selfnorm,
    const float* __restrict__ bias, float* __restrict__ out) {
    int wid = (blockIdx.x * 256 + threadIdx.x) >> 6;
    int lane = threadIdx.x & 63;
    int c = __builtin_amdgcn_readfirstlane(wid);
    if (c >= N_NODES) return;
    int beg = col_start[c], end = col_start[c + 1];
    float v[5] = {0.0f, 0.0f, 0.0f, 0.0f, 0.0f};
    int i = beg;
    for (; i + 4 <= end; i += 4) {
        int2 e0 = edge_pack[i], e1 = edge_pack[i + 1];
        int2 e2 = edge_pack[i + 2], e3 = edge_pack[i + 3];
        const float* h0 = hw + (size_t)e0.x * HIDP;
        const float* h1 = hw + (size_t)e1.x * HIDP;
        const float* h2 = hw + (size_t)e2.x * HIDP;
        const float* h3 = hw + (size_t)e3.x * HIDP;
        float n0 = __int_as_float(e0.y), n1 = __int_as_float(e1.y);
        float n2 = __int_as_float(e2.y), n3 = __int_as_float(e3.y);
#pragma unroll
        for (int j = 0; j < 5; ++j) {
            int col = lane + 64 * j;
            if (col < HIDP) {
                float s = v[j];
                s = fmaf(n0, h0[col], s);
                s = fmaf(n1, h1[col], s);
                s = fmaf(n2, h2[col], s);
                s = fmaf(n3, h3[col], s);
                v[j] = s;
            }
        }
    }
    for (; i < end; ++i) {
        int2 e0 = edge_pack[i];
        const float* h0 = hw + (size_t)e0.x * HIDP;
        float n0 = __int_as_float(e0.y);
#pragma unroll
        for (int j = 0; j < 5; ++j) {
            int col = lane + 64 * j;
            if (col < HIDP) v[j] = fmaf(n0, h0[col], v[j]);
        }
    }
    float sn = selfnorm[c];
    const float* sp = hw + (size_t)c * HIDP;
#pragma unroll
    for (int j = 0; j < 5; ++j) {
        int col = lane + 64 * j;
        if (col < HIDP) {
            float h = v[j] + sn * sp[col] + ((col < HID) ? bias[col] : 0.0f);
            out[(size_t)c * HIDP + col] = fmaxf(h, 0.0f);
        }
    }
}

// colsum over Part A final h + fold of g_part, both into g_sum
__global__ void k_colsum(const float* __restrict__ h, const float* __restrict__ g_part,
                         float* __restrict__ g_sum) {
    int b = blockIdx.x, t = threadIdx.x;
    if (b < 157) {
        int r0 = b * 64;
        float s0 = 0.0f, s1 = 0.0f;
        for (int r = 0; r < 64; ++r) {
            int gr = r0 + r;
            if (gr < N_NODES) {
                s0 += h[(size_t)gr * HIDP + t];
                if (t < HIDP - 256) s1 += h[(size_t)gr * HIDP + 256 + t];
            }
        }
        if (t < HID) atomicAdd(&g_sum[t], s0);
        if (t < HIDP - 256 && 256 + t < HID) atomicAdd(&g_sum[256 + t], s1);
    } else {
        int cc = (b - 157) * 256 + t;
        if (cc < HID) {
            float s = 0.0f;
            for (int g = 0; g < 64; ++g) s += g_part[g * HIDP + cc];
            atomicAdd(&g_sum[cc], s);
        }
    }
}

__global__ void k_head(const float* __restrict__ g_sum,
                       const float* __restrict__ lin1_w, const float* __restrict__ lin1_b,
                       const float* __restrict__ lin2_w, const float* __restrict__ lin2_b,
                       float* __restrict__ out) {
    __shared__ float g2[32];
    int t = threadIdx.x;
    const float inv = 1.0f / (float)N_EDGES;
    if (t < 32) {
        float a = lin1_b[t];
        for (int d = 0; d < HID; ++d) a = fmaf(g_sum[d] * inv, lin1_w[d * 32 + t], a);
        g2[t] = fmaxf(a, 0.0f);
    }
    __syncthreads();
    if (t < 2) {
        float p = lin2_b[t];
        for (int j = 0; j < 32; ++j) p = fmaf(g2[j], lin2_w[j * 2 + t], p);
        out[t] = p;
    }
}

// ---------------------------------------------------------------------------

extern "C" void kernel_launch(void* const* d_in, const int* in_sizes, int n_in,
                              void* d_out, int out_size, void* d_ws, size_t ws_size,
                              hipStream_t stream) {
    (void)in_sizes; (void)n_in; (void)out_size; (void)ws_size;
    const int* edge_index = (const int*)d_in[1];
    const float* edge_attr = (const float*)d_in[2];
    const float* edge_w = (const float*)d_in[6];
    const float* edge_b = (const float*)d_in[7];
    const float* gcn0_w = (const float*)d_in[8];
    const float* gcn0_b = (const float*)d_in[9];
    const float* gcn_w = (const float*)d_in[10];
    const float* gcn_b = (const float*)d_in[11];
    const float* lin1_w = (const float*)d_in[12];
    const float* lin1_b = (const float*)d_in[13];
    const float* lin2_w = (const float*)d_in[14];
    const float* lin2_b = (const float*)d_in[15];

    char* ws = (char*)d_ws;
    size_t off = 0;
    auto alloc = [&](size_t bytes) {
        void* p = ws + off;
        off = (off + bytes + 255) & ~(size_t)255;
        return p;
    };
    float* hA = (float*)alloc((size_t)N_NODES * HIDP * 4);
    float* hB = (float*)alloc((size_t)N_NODES * HIDP * 4);
    float* hw = (float*)alloc((size_t)N_NODES * HIDP * 4);
    int2* edge_pack = (int2*)alloc((size_t)N_EDGES * 8);
    int* cnt = (int*)alloc((size_t)N_NODES * 4);
    int* col_start = (int*)alloc((size_t)(N_NODES + 1) * 4);
    int* cursor = (int*)alloc((size_t)N_NODES * 4);
    float* dinv = (float*)alloc((size_t)N_NODES * 4);
    float* selfnorm = (float*)alloc((size_t)N_NODES * 4);
    float* g_sum = (float*)alloc((size_t)HIDP * 4);
    short* wt0 = (short*)alloc((size_t)38912);
    short* wtl = (short*)alloc((size_t)4 * 389120);
    float* g_part = (float*)alloc((size_t)64 * HIDP * 4);

    const int* row = edge_index;
    const int* col = edge_index + N_EDGES;

    hipMemsetAsync(cnt, 0, N_NODES * 4, stream);
    hipMemsetAsync(g_sum, 0, HIDP * 4, stream);
    hipMemsetAsync(g_part, 0, 64 * HIDP * 4, stream);

    k_wt<<<(1216 + 48640 + 255) / 256, 256, 0, stream>>>(gcn0_w, gcn_w, wt0, wtl);
    k_count<<<(N_EDGES + 255) / 256, 256, 0, stream>>>(col, cnt);
    k_scan<<<1, 256, 0, stream>>>(cnt, col_start, cursor, dinv, selfnorm);
    k_fill<<<(N_EDGES + 255) / 256, 256, 0, stream>>>(row, col, cursor, dinv, edge_pack);

    // Part B: 3125 blocks x 8 waves, B-double-buffered runtime k-loop
    k_partB_mfma<<<NPARTB / RB, 512, 0, stream>>>(edge_attr, edge_w, edge_b,
                                                  wt0, wtl, gcn0_b, gcn_b, g_part);

    // Part A: coupled top-10000 rows
    const int gA_blocks = (N_NODES + RB - 1) / RB;
    const int aggA_blocks = (N_NODES + 3) / 4;
    k_gemmA<true><<<gA_blocks, 512, 0, stream>>>(nullptr, edge_attr, edge_w, edge_b, wt0, hw);
    k_aggA<<<aggA_blocks, 256, 0, stream>>>(hw, col_start, edge_pack, selfnorm, gcn0_b, hA);
    float* curr = hA;
    float* next = hB;
    for (int l = 1; l < 5; ++l) {
        k_gemmA<false><<<gA_blocks, 512, 0, stream>>>(curr, edge_attr, edge_w, edge_b,
                                                      wtl + (size_t)(l - 1) * 194560, hw);
        k_aggA<<<aggA_blocks, 256, 0, stream>>>(hw, col_start, edge_pack, selfnorm,
                                                gcn_b + (l - 1) * HID, next);
        float* tmp = curr; curr = next; next = tmp;
    }
    k_colsum<<<159, 256, 0, stream>>>(curr, g_part, g_sum);
    k_head<<<1, 64, 0, stream>>>(g_sum, lin1_w, lin1_b, lin2_w, lin2_b, (float*)d_out);
}

// Round 7
// 545.606 us; speedup vs baseline: 1.7914x; 1.7914x over previous
//
#include <hip/hip_runtime.h>
#include <hip/hip_bf16.h>

#define N_NODES 10000
#define N_EDGES 160000
#define HID 300
#define HIDP 304   // padded hidden dim (Part A buffers)
#define NPARTB (N_EDGES - N_NODES)   // 150000 independent rows
#define RB 64      // rows per GCN block (4 M-tiles)
#define KS 328     // H-plane k-stride in shorts (656B rows -> 2-way banks, free)

typedef __attribute__((ext_vector_type(8))) short short8;
typedef __attribute__((ext_vector_type(4))) float f32x4;

#define MFMA_B16(a, b, c) __builtin_amdgcn_mfma_f32_16x16x32_bf16(a, b, c, 0, 0, 0)

__device__ __forceinline__ short bf16r(float x) {
    unsigned u = __float_as_uint(x);
    return (short)((u + 0x7fffu + ((u >> 16) & 1u)) >> 16);
}

__device__ __forceinline__ float b2f(unsigned short u) {
    return __uint_as_float(((unsigned)u) << 16);
}

__device__ __forceinline__ void split1(float x, short& hi, short& lo) {
    short h = bf16r(x);
    float hf = __uint_as_float(((unsigned)(unsigned short)h) << 16);
    hi = h;
    lo = bf16r(x - hf);
}

// ---------------------------------------------------------------------------
// prep kernels
// ---------------------------------------------------------------------------

__global__ void k_count(const int* __restrict__ col, int* __restrict__ cnt) {
    int e = blockIdx.x * 256 + threadIdx.x;
    if (e < N_EDGES) atomicAdd(&cnt[col[e]], 1);
}

__global__ void k_scan(const int* __restrict__ cnt, int* __restrict__ col_start,
                       int* __restrict__ cursor, float* __restrict__ dinv,
                       float* __restrict__ selfnorm) {
    __shared__ int wsum[4];
    int t = threadIdx.x;
    int lane = t & 63, w = t >> 6;
    int carry = 0;
    for (int base = 0; base < N_NODES; base += 256) {
        int i = base + t;
        int v = (i < N_NODES) ? cnt[i] : 0;
        int s = v;
#pragma unroll
        for (int d = 1; d < 64; d <<= 1) {
            int n = __shfl_up(s, d, 64);
            if (lane >= d) s += n;
        }
        if (lane == 63) wsum[w] = s;
        __syncthreads();
        int woff = 0;
#pragma unroll
        for (int k = 0; k < 4; ++k)
            if (k < w) woff += wsum[k];
        int total = wsum[0] + wsum[1] + wsum[2] + wsum[3];
        if (i < N_NODES) {
            int excl = carry + woff + s - v;
            col_start[i] = excl;
            cursor[i] = excl;
            float dd = (float)v + 1.0f;
            dinv[i] = rsqrtf(dd);
            selfnorm[i] = 1.0f / dd;
        }
        carry += total;
        __syncthreads();
    }
    if (t == 0) col_start[N_NODES] = carry;
}

__global__ void k_fill(const int* __restrict__ row, const int* __restrict__ col,
                       int* __restrict__ cursor, const float* __restrict__ dinv,
                       int2* __restrict__ edge_pack) {
    int e = blockIdx.x * 256 + threadIdx.x;
    if (e < N_EDGES) {
        int c = col[e], r = row[e];
        int p = atomicAdd(&cursor[c], 1);
        edge_pack[p] = make_int2(r, __float_as_int(dinv[r] * dinv[c]));
    }
}

// ---------------------------------------------------------------------------
// Weight pre-split (layout verified R2-R6):
// wt0 [nt:19][h:2][q:4][n16:16][j:8] shorts; wtl [l:4][chunk:10][nt:19][...]
// ---------------------------------------------------------------------------
__global__ void k_wt(const float* __restrict__ g0w, const float* __restrict__ gw,
                     short* __restrict__ wt0, short* __restrict__ wtl) {
    int idx = blockIdx.x * 256 + threadIdx.x;
    if (idx < 1216) {
        int n16 = idx & 15, q = (idx >> 4) & 3, nt = idx >> 6;
        int n = nt * 16 + n16;
        short* hd = wt0 + (size_t)(nt * 8 + q) * 128 + n16 * 8;
        short* ld = wt0 + (size_t)(nt * 8 + 4 + q) * 128 + n16 * 8;
#pragma unroll
        for (int j = 0; j < 8; ++j) {
            int k = q * 8 + j;
            float f = (n < HID) ? g0w[k * HID + n] : 0.0f;
            short hi, lo;
            split1(f, hi, lo);
            hd[j] = hi;
            ld[j] = lo;
        }
    } else if (idx < 1216 + 48640) {
        int i = idx - 1216;
        int n16 = i & 15; i >>= 4;
        int q = i & 3; i >>= 2;
        int nt = i % 19; i /= 19;
        int chunk = i % 10;
        int l = i / 10;
        int n = nt * 16 + n16;
        int cnt_idx = chunk * 19 + nt;
        short* base = wtl + (size_t)l * 194560;
        short* hd = base + (size_t)(cnt_idx * 8 + q) * 128 + n16 * 8;
        short* ld = base + (size_t)(cnt_idx * 8 + 4 + q) * 128 + n16 * 8;
#pragma unroll
        for (int j = 0; j < 8; ++j) {
            int k = chunk * 32 + q * 8 + j;
            float f = (k < HID && n < HID) ? gw[((size_t)l * HID + k) * HID + n] : 0.0f;
            short hi, lo;
            split1(f, hi, lo);
            hd[j] = hi;
            ld[j] = lo;
        }
    }
}

// ---------------------------------------------------------------------------
// GCN core: 8 waves / 64 rows (4 M-tiles per wave) / A plain-bf16 plane in
// LDS / B split hi+lo (2-term MFMA: A*Bh + A*Bl, fp32 acc).
// Single-buffered, runtime chunk loop (#pragma unroll 1) — the R5/R6 lesson:
// any double-buffer on top of 48-AGPR acc spills at the 128-reg/wave cap.
// Regs: acc 48 (AGPR) + B 12 + A 16 + addr ~15 ≈ 95 total.
// ---------------------------------------------------------------------------

template <int NTC>
__device__ __forceinline__ void kloop(const short* __restrict__ wp, int nch,
                                      const short* Hh,
                                      int nt0, int quad, int l16,
                                      f32x4 (&acc)[4][3]) {
#pragma unroll
    for (int mt = 0; mt < 4; ++mt)
#pragma unroll
        for (int i = 0; i < NTC; ++i)
#pragma unroll
            for (int r = 0; r < 4; ++r) acc[mt][i][r] = 0.0f;
#pragma unroll 1
    for (int c = 0; c < nch; ++c) {
        short8 ah[4];
#pragma unroll
        for (int mt = 0; mt < 4; ++mt)
            ah[mt] = *(const short8*)&Hh[(mt * 16 + l16) * KS + c * 32 + quad * 8];
        const short* cb = wp + (size_t)(c * 19 + nt0) * 1024 + quad * 128 + l16 * 8;
        short8 bb[NTC];
#pragma unroll
        for (int i = 0; i < NTC; ++i) bb[i] = *(const short8*)(cb + (size_t)i * 1024);
#pragma unroll
        for (int mt = 0; mt < 4; ++mt)
#pragma unroll
            for (int i = 0; i < NTC; ++i)
                acc[mt][i] = MFMA_B16(ah[mt], bb[i], acc[mt][i]);
#pragma unroll
        for (int i = 0; i < NTC; ++i) bb[i] = *(const short8*)(cb + (size_t)i * 1024 + 512);
#pragma unroll
        for (int mt = 0; mt < 4; ++mt)
#pragma unroll
            for (int i = 0; i < NTC; ++i)
                acc[mt][i] = MFMA_B16(ah[mt], bb[i], acc[mt][i]);
    }
}

template <int NTC>
__device__ __forceinline__ void gcn_epilogue(const float* __restrict__ bias,
                                             int nt0, int quad, int l16,
                                             f32x4 (&acc)[4][3], short* Hh) {
#pragma unroll
    for (int i = 0; i < NTC; ++i) {
        int c = (nt0 + i) * 16 + l16;
        float b = (c < HID) ? bias[c] : 0.0f;
#pragma unroll
        for (int mt = 0; mt < 4; ++mt)
#pragma unroll
            for (int r = 0; r < 4; ++r) {
                float v = fmaxf(acc[mt][i][r] + b, 0.0f);
                Hh[(mt * 16 + quad * 4 + r) * KS + c] = bf16r(v);
            }
    }
}

template <int NTC>
__device__ __forceinline__ void gcn_final(const float* __restrict__ bias,
                                          int nt0, int quad, int l16,
                                          int valid, int slot,
                                          f32x4 (&acc)[4][3],
                                          float* __restrict__ g_part) {
#pragma unroll
    for (int i = 0; i < NTC; ++i) {
        int c = (nt0 + i) * 16 + l16;
        float b = (c < HID) ? bias[c] : 0.0f;
        float s = 0.0f;
#pragma unroll
        for (int mt = 0; mt < 4; ++mt)
#pragma unroll
            for (int r = 0; r < 4; ++r) {
                int rr = mt * 16 + quad * 4 + r;
                float v = fmaxf(acc[mt][i][r] + b, 0.0f);
                if (rr < valid) s += v;
            }
        s += __shfl_xor(s, 16, 64);
        s += __shfl_xor(s, 32, 64);
        if (quad == 0 && c < HID)
            atomicAdd(&g_part[slot * HIDP + c], s);
    }
}

// ---------------------------------------------------------------------------
// Part B: fused 5-layer; inline edge-embed; 2344 blocks (last has 48 rows).
// ---------------------------------------------------------------------------
__global__ __launch_bounds__(512, 4) void k_partB_mfma(
    const float* __restrict__ edge_attr,
    const float* __restrict__ edge_w,
    const float* __restrict__ edge_b,
    const short* __restrict__ wt0,
    const short* __restrict__ wtl,
    const float* __restrict__ b0,
    const float* __restrict__ gb,
    float* __restrict__ g_part) {
    __shared__ short Hh[RB * KS];   // 41984 B
    int t = threadIdx.x;
    int lane = t & 63, w = t >> 6;
    int l16 = lane & 15, quad = lane >> 4;
    int base = N_NODES + blockIdx.x * RB;
    int nt0 = (w < 3) ? w * 3 : 9 + (w - 3) * 2;
    int valid = N_EDGES - base;   // >= 64 for all but last block

    // inline edge embedding -> bf16 plane (64 rows x 32 cols), 1 unit/thread
    {
        int r = t >> 3, c4 = (t & 7) * 4;
        int gr = base + r;
        float a0 = 0.f, a1 = 0.f, a2 = 0.f;
        if (gr < N_EDGES) {
            const float* ar = edge_attr + (size_t)gr * 3;
            a0 = ar[0]; a1 = ar[1]; a2 = ar[2];
        }
#pragma unroll
        for (int j = 0; j < 4; ++j) {
            int cc = c4 + j;
            float v = 0.0f;
            if (gr < N_EDGES) {
                v = edge_b[cc];
                v = fmaf(a0, edge_w[cc], v);
                v = fmaf(a1, edge_w[32 + cc], v);
                v = fmaf(a2, edge_w[64 + cc], v);
            }
            Hh[r * KS + cc] = bf16r(v);
        }
    }
    for (int i = t; i < RB * 24; i += 512) {
        int r = i / 24, k = 304 + i % 24;
        Hh[r * KS + k] = 0;
    }
    __syncthreads();

    f32x4 acc[4][3];
    if (w < 3) kloop<3>(wt0, 1, Hh, nt0, quad, l16, acc);
    else       kloop<2>(wt0, 1, Hh, nt0, quad, l16, acc);
    __syncthreads();
    if (w < 3) gcn_epilogue<3>(b0, nt0, quad, l16, acc, Hh);
    else       gcn_epilogue<2>(b0, nt0, quad, l16, acc, Hh);
    __syncthreads();

    for (int l = 0; l < 4; ++l) {
        const short* wp = wtl + (size_t)l * 194560;
        const float* bias = gb + l * HID;
        if (w < 3) kloop<3>(wp, 10, Hh, nt0, quad, l16, acc);
        else       kloop<2>(wp, 10, Hh, nt0, quad, l16, acc);
        __syncthreads();
        if (l < 3) {
            if (w < 3) gcn_epilogue<3>(bias, nt0, quad, l16, acc, Hh);
            else       gcn_epilogue<2>(bias, nt0, quad, l16, acc, Hh);
            __syncthreads();
        } else {
            int slot = (blockIdx.x + w) & 63;
            if (w < 3) gcn_final<3>(bias, nt0, quad, l16, valid, slot, acc, g_part);
            else       gcn_final<2>(bias, nt0, quad, l16, valid, slot, acc, g_part);
        }
    }
}

// ---------------------------------------------------------------------------
// Part A GEMM: output hw as bf16 (pre-bias raw acc rounded).
// ---------------------------------------------------------------------------
template <int NTC>
__device__ __forceinline__ void gemm_out(int base, int nt0, int quad, int l16,
                                         f32x4 (&acc)[4][3],
                                         unsigned short* __restrict__ HW) {
#pragma unroll
    for (int i = 0; i < NTC; ++i) {
        int c = (nt0 + i) * 16 + l16;
#pragma unroll
        for (int mt = 0; mt < 4; ++mt)
#pragma unroll
            for (int r = 0; r < 4; ++r) {
                int gm = base + mt * 16 + quad * 4 + r;
                if (gm < N_NODES)
                    HW[(size_t)gm * HIDP + c] = (unsigned short)bf16r(acc[mt][i][r]);
            }
    }
}

template <bool L0>
__global__ __launch_bounds__(512, 4) void k_gemmA(
    const unsigned short* __restrict__ A,   // bf16 [N_NODES][HIDP] (hidden layers)
    const float* __restrict__ edge_attr,
    const float* __restrict__ edge_w,
    const float* __restrict__ edge_b,
    const short* __restrict__ wt,
    unsigned short* __restrict__ HW) {
    __shared__ short Hh[RB * KS];
    int t = threadIdx.x;
    int lane = t & 63, w = t >> 6;
    int l16 = lane & 15, quad = lane >> 4;
    int base = blockIdx.x * RB;
    int nt0 = (w < 3) ? w * 3 : 9 + (w - 3) * 2;

    if (L0) {
        int r = t >> 3, c4 = (t & 7) * 4;
        int gr = base + r;
        float a0 = 0.f, a1 = 0.f, a2 = 0.f;
        if (gr < N_NODES) {
            const float* ar = edge_attr + (size_t)gr * 3;
            a0 = ar[0]; a1 = ar[1]; a2 = ar[2];
        }
#pragma unroll
        for (int j = 0; j < 4; ++j) {
            int cc = c4 + j;
            float v = 0.0f;
            if (gr < N_NODES) {
                v = edge_b[cc];
                v = fmaf(a0, edge_w[cc], v);
                v = fmaf(a1, edge_w[32 + cc], v);
                v = fmaf(a2, edge_w[64 + cc], v);
            }
            Hh[r * KS + cc] = bf16r(v);
        }
    } else {
        // copy bf16 rows (76 ushort4 units per row)
        for (int idx = t; idx < RB * 76; idx += 512) {
            int r = idx / 76, c4 = (idx % 76) * 4;
            int gr = base + r;
            ushort4 v = make_ushort4(0, 0, 0, 0);
            if (gr < N_NODES) v = *(const ushort4*)(A + (size_t)gr * HIDP + c4);
            short* d = &Hh[r * KS + c4];
            d[0] = (short)v.x; d[1] = (short)v.y; d[2] = (short)v.z; d[3] = (short)v.w;
        }
        for (int i = t; i < RB * 24; i += 512) {
            int r = i / 24, k = 304 + i % 24;
            Hh[r * KS + k] = 0;
        }
    }
    __syncthreads();

    f32x4 acc[4][3];
    if (L0) {
        if (w < 3) kloop<3>(wt, 1, Hh, nt0, quad, l16, acc);
        else       kloop<2>(wt, 1, Hh, nt0, quad, l16, acc);
    } else {
        if (w < 3) kloop<3>(wt, 10, Hh, nt0, quad, l16, acc);
        else       kloop<2>(wt, 10, Hh, nt0, quad, l16, acc);
    }
    if (w < 3) gemm_out<3>(base, nt0, quad, l16, acc, HW);
    else       gemm_out<2>(base, nt0, quad, l16, acc, HW);
}

// ---------------------------------------------------------------------------
// Part A aggregation: wave per node; hw gathered as bf16 (half the bytes);
// output written as bf16 (next gemm stages it directly).
// ---------------------------------------------------------------------------
__global__ __launch_bounds__(256) void k_aggA(
    const unsigned short* __restrict__ hw, const int* __restrict__ col_start,
    const int2* __restrict__ edge_pack, const float* __restrict__ selfnorm,
    const float* __restrict__ bias, unsigned short* __restrict__ out) {
    int wid = (blockIdx.x * 256 + threadIdx.x) >> 6;
    int lane = threadIdx.x & 63;
    int c = __builtin_amdgcn_readfirstlane(wid);
    if (c >= N_NODES) return;
    int beg = col_start[c], end = col_start[c + 1];
    float v[5] = {0.0f, 0.0f, 0.0f, 0.0f, 0.0f};
    int i = beg;
    for (; i + 4 <= end; i += 4) {
        int2 e0 = edge_pack[i], e1 = edge_pack[i + 1];
        int2 e2 = edge_pack[i + 2], e3 = edge_pack[i + 3];
        const unsigned short* h0 = hw + (size_t)e0.x * HIDP;
        const unsigned short* h1 = hw + (size_t)e1.x * HIDP;
        const unsigned short* h2 = hw + (size_t)e2.x * HIDP;
        const unsigned short* h3 = hw + (size_t)e3.x * HIDP;
        float n0 = __int_as_float(e0.y), n1 = __int_as_float(e1.y);
        float n2 = __int_as_float(e2.y), n3 = __int_as_float(e3.y);
#pragma unroll
        for (int j = 0; j < 5; ++j) {
            int col = lane + 64 * j;
            if (col < HIDP) {
                float s = v[j];
                s = fmaf(n0, b2f(h0[col]), s);
                s = fmaf(n1, b2f(h1[col]), s);
                s = fmaf(n2, b2f(h2[col]), s);
                s = fmaf(n3, b2f(h3[col]), s);
                v[j] = s;
            }
        }
    }
    for (; i < end; ++i) {
        int2 e0 = edge_pack[i];
        const unsigned short* h0 = hw + (size_t)e0.x * HIDP;
        float n0 = __int_as_float(e0.y);
#pragma unroll
        for (int j = 0; j < 5; ++j) {
            int col = lane + 64 * j;
            if (col < HIDP) v[j] = fmaf(n0, b2f(h0[col]), v[j]);
        }
    }
    float sn = selfnorm[c];
    const unsigned short* sp = hw + (size_t)c * HIDP;
#pragma unroll
    for (int j = 0; j < 5; ++j) {
        int col = lane + 64 * j;
        if (col < HIDP) {
            float h = v[j] + sn * b2f(sp[col]) + ((col < HID) ? bias[col] : 0.0f);
            out[(size_t)c * HIDP + col] = (unsigned short)bf16r(fmaxf(h, 0.0f));
        }
    }
}

// colsum over Part A final h (bf16) + fold of g_part, both into g_sum
__global__ void k_colsum(const unsigned short* __restrict__ h,
                         const float* __restrict__ g_part,
                         float* __restrict__ g_sum) {
    int b = blockIdx.x, t = threadIdx.x;
    if (b < 157) {
        int r0 = b * 64;
        float s0 = 0.0f, s1 = 0.0f;
        for (int r = 0; r < 64; ++r) {
            int gr = r0 + r;
            if (gr < N_NODES) {
                s0 += b2f(h[(size_t)gr * HIDP + t]);
                if (t < HIDP - 256) s1 += b2f(h[(size_t)gr * HIDP + 256 + t]);
            }
        }
        if (t < HID) atomicAdd(&g_sum[t], s0);
        if (t < HIDP - 256 && 256 + t < HID) atomicAdd(&g_sum[256 + t], s1);
    } else {
        int cc = (b - 157) * 256 + t;
        if (cc < HID) {
            float s = 0.0f;
            for (int g = 0; g < 64; ++g) s += g_part[g * HIDP + cc];
            atomicAdd(&g_sum[cc], s);
        }
    }
}

__global__ void k_head(const float* __restrict__ g_sum,
                       const float* __restrict__ lin1_w, const float* __restrict__ lin1_b,
                       const float* __restrict__ lin2_w, const float* __restrict__ lin2_b,
                       float* __restrict__ out) {
    __shared__ float g2[32];
    int t = threadIdx.x;
    const float inv = 1.0f / (float)N_EDGES;
    if (t < 32) {
        float a = lin1_b[t];
        for (int d = 0; d < HID; ++d) a = fmaf(g_sum[d] * inv, lin1_w[d * 32 + t], a);
        g2[t] = fmaxf(a, 0.0f);
    }
    __syncthreads();
    if (t < 2) {
        float p = lin2_b[t];
        for (int j = 0; j < 32; ++j) p = fmaf(g2[j], lin2_w[j * 2 + t], p);
        out[t] = p;
    }
}

// ---------------------------------------------------------------------------

extern "C" void kernel_launch(void* const* d_in, const int* in_sizes, int n_in,
                              void* d_out, int out_size, void* d_ws, size_t ws_size,
                              hipStream_t stream) {
    (void)in_sizes; (void)n_in; (void)out_size; (void)ws_size;
    const int* edge_index = (const int*)d_in[1];
    const float* edge_attr = (const float*)d_in[2];
    const float* edge_w = (const float*)d_in[6];
    const float* edge_b = (const float*)d_in[7];
    const float* gcn0_w = (const float*)d_in[8];
    const float* gcn0_b = (const float*)d_in[9];
    const float* gcn_w = (const float*)d_in[10];
    const float* gcn_b = (const float*)d_in[11];
    const float* lin1_w = (const float*)d_in[12];
    const float* lin1_b = (const float*)d_in[13];
    const float* lin2_w = (const float*)d_in[14];
    const float* lin2_b = (const float*)d_in[15];

    char* ws = (char*)d_ws;
    size_t off = 0;
    auto alloc = [&](size_t bytes) {
        void* p = ws + off;
        off = (off + bytes + 255) & ~(size_t)255;
        return p;
    };
    unsigned short* hA = (unsigned short*)alloc((size_t)N_NODES * HIDP * 2);
    unsigned short* hB = (unsigned short*)alloc((size_t)N_NODES * HIDP * 2);
    unsigned short* hw = (unsigned short*)alloc((size_t)N_NODES * HIDP * 2);
    int2* edge_pack = (int2*)alloc((size_t)N_EDGES * 8);
    int* cnt = (int*)alloc((size_t)N_NODES * 4);
    int* col_start = (int*)alloc((size_t)(N_NODES + 1) * 4);
    int* cursor = (int*)alloc((size_t)N_NODES * 4);
    float* dinv = (float*)alloc((size_t)N_NODES * 4);
    float* selfnorm = (float*)alloc((size_t)N_NODES * 4);
    float* g_sum = (float*)alloc((size_t)HIDP * 4);
    short* wt0 = (short*)alloc((size_t)38912);
    short* wtl = (short*)alloc((size_t)4 * 389120);
    float* g_part = (float*)alloc((size_t)64 * HIDP * 4);

    const int* row = edge_index;
    const int* col = edge_index + N_EDGES;

    hipMemsetAsync(cnt, 0, N_NODES * 4, stream);
    hipMemsetAsync(g_sum, 0, HIDP * 4, stream);
    hipMemsetAsync(g_part, 0, 64 * HIDP * 4, stream);

    k_wt<<<(1216 + 48640 + 255) / 256, 256, 0, stream>>>(gcn0_w, gcn_w, wt0, wtl);
    k_count<<<(N_EDGES + 255) / 256, 256, 0, stream>>>(col, cnt);
    k_scan<<<1, 256, 0, stream>>>(cnt, col_start, cursor, dinv, selfnorm);
    k_fill<<<(N_EDGES + 255) / 256, 256, 0, stream>>>(row, col, cursor, dinv, edge_pack);

    // Part B: 2344 blocks x 8 waves, 2-term split-bf16, single-buffered
    k_partB_mfma<<<(NPARTB + RB - 1) / RB, 512, 0, stream>>>(
        edge_attr, edge_w, edge_b, wt0, wtl, gcn0_b, gcn_b, g_part);

    // Part A: coupled top-10000 rows
    const int gA_blocks = (N_NODES + RB - 1) / RB;   // 157
    const int aggA_blocks = (N_NODES + 3) / 4;
    k_gemmA<true><<<gA_blocks, 512, 0, stream>>>(nullptr, edge_attr, edge_w, edge_b, wt0, hw);
    k_aggA<<<aggA_blocks, 256, 0, stream>>>(hw, col_start, edge_pack, selfnorm, gcn0_b, hA);
    unsigned short* curr = hA;
    unsigned short* next = hB;
    for (int l = 1; l < 5; ++l) {
        k_gemmA<false><<<gA_blocks, 512, 0, stream>>>(curr, edge_attr, edge_w, edge_b,
                                                      wtl + (size_t)(l - 1) * 194560, hw);
        k_aggA<<<aggA_blocks, 256, 0, stream>>>(hw, col_start, edge_pack, selfnorm,
                                                gcn_b + (l - 1) * HID, next);
        unsigned short* tmp = curr; curr = next; next = tmp;
    }
    k_colsum<<<159, 256, 0, stream>>>(curr, g_part, g_sum);
    k_head<<<1, 64, 0, stream>>>(g_sum, lin1_w, lin1_b, lin2_w, lin2_b, (float*)d_out);
}